// Round 1
// baseline (270.143 us; speedup 1.0000x reference)
//
#include <hip/hip_runtime.h>

// Problem constants
#define N_TOT 32768          // B*H*W
#define KNUM 1024
#define DDIM 64
#define OUT_OFF_Q 0          // quantized (straight-through == quantized fwd) [B,D,H,W]
#define OUT_OFF_VQ 2097152   // scalar vq_loss
#define OUT_OFF_PPL 2097153  // scalar perplexity
#define OUT_OFF_ENC 2097154  // encoded one-hot [N, K]

// Main fused kernel:
//  - 512 blocks x 512 threads; block owns 64 consecutive n = b*1024 + hw
//  - wave w (0..7) handles k-chunk [w*128, w*128+128)
//  - lane l handles n = blk*64 + l (x kept in 64 VGPRs)
//  - e rows read via scalar loads (k is wave-uniform by construction)
//  - epilogue: quantized store (d split across waves), encoded one-hot rows
//    (8 rows per wave, coalesced float4), counts histogram + loss atomics
__global__ __launch_bounds__(512, 4) void vq_main(
    const float* __restrict__ X, const float* __restrict__ E,
    float* __restrict__ out, int* __restrict__ counts,
    float* __restrict__ lossSum)
{
    __shared__ float s_ee[1024];
    __shared__ float s_val[8][64];
    __shared__ int   s_idx[8][64];

    const int t = threadIdx.x;
    const int l = t & 63;
    // force wave-uniform w into an SGPR so e-row addresses become scalar loads
    const int w = __builtin_amdgcn_readfirstlane(t >> 6);
    const int n = blockIdx.x * 64 + l;
    const int b = n >> 10;        // all lanes in block share b (64 | 1024)
    const int hw = n & 1023;

    // --- precompute ||e_k||^2 into LDS (each thread does 2 rows) ---
    for (int kk = t; kk < 1024; kk += 512) {
        const float4* ep4 = (const float4*)(E + (kk << 6));
        float s = 0.f;
        #pragma unroll
        for (int j = 0; j < 16; ++j) {
            float4 v = ep4[j];
            s = fmaf(v.x, v.x, s); s = fmaf(v.y, v.y, s);
            s = fmaf(v.z, v.z, s); s = fmaf(v.w, v.w, s);
        }
        s_ee[kk] = s;
    }

    // --- load this lane's x vector into registers (coalesced across hw) ---
    float x[64];
    const float* xp = X + (size_t)b * 65536 + hw;
    #pragma unroll
    for (int d = 0; d < 64; ++d) x[d] = xp[(size_t)d * 1024];

    __syncthreads();

    // --- argmin over this wave's k-chunk ---
    const int k0 = w << 7;
    float best = 3.4e38f;
    int bidx = 0;
    #pragma unroll 2
    for (int k = k0; k < k0 + 128; ++k) {
        const float* ep = E + (k << 6);   // scalar address -> s_load
        float dot = 0.f;
        #pragma unroll
        for (int d = 0; d < 64; ++d) dot = fmaf(x[d], ep[d], dot);
        float val = fmaf(-2.f, dot, s_ee[k]);   // ||e||^2 - 2 x.e
        if (val < best) { best = val; bidx = k; }   // strict < : first occurrence
    }
    s_val[w][l] = best;
    s_idx[w][l] = bidx;
    __syncthreads();

    // --- cross-wave reduce (wave 0), tie-break to lowest k ---
    if (w == 0) {
        float fv = s_val[0][l]; int fi0 = s_idx[0][l];
        #pragma unroll
        for (int j = 1; j < 8; ++j) {
            float v = s_val[j][l]; int i = s_idx[j][l];
            if (v < fv || (v == fv && i < fi0)) { fv = v; fi0 = i; }
        }
        s_idx[0][l] = fi0;   // publish final index
    }
    __syncthreads();

    const int fi = s_idx[0][l];   // final code index for this lane's n

    // --- counts histogram (one atomic per n) ---
    if (w == 0) atomicAdd(&counts[fi], 1);

    // --- quantized store + loss partial: wave w handles d in [8w, 8w+8) ---
    {
        float lsum = 0.f;
        float* op = out + OUT_OFF_Q + (size_t)b * 65536 + hw;
        const int d0 = w << 3;
        #pragma unroll
        for (int dd = 0; dd < 8; ++dd) {
            const int d = d0 + dd;
            float q = E[((size_t)fi << 6) + d];     // per-lane gather (L2)
            op[(size_t)d * 1024] = q;               // coalesced store
            float xv = xp[(size_t)d * 1024];        // L1 hit (re-read, avoids
                                                    // dynamic reg-array index)
            float diff = q - xv;
            lsum = fmaf(diff, diff, lsum);
        }
        #pragma unroll
        for (int off = 32; off; off >>= 1) lsum += __shfl_down(lsum, off);
        if (l == 0) atomicAdd(lossSum, lsum);
    }

    // --- encoded one-hot rows: wave w writes rows [8w, 8w+8), coalesced ---
    {
        float* enc = out + OUT_OFF_ENC;
        const int rbase = w << 3;
        for (int rr = 0; rr < 8; ++rr) {
            const int r = rbase + rr;
            const int ridx = s_idx[0][r];           // LDS broadcast
            float* erow = enc + ((size_t)(blockIdx.x * 64 + r) << 10);
            #pragma unroll
            for (int c = 0; c < 4; ++c) {
                const int kb = (c << 8) + (l << 2);
                float4 v = make_float4(0.f, 0.f, 0.f, 0.f);
                const int dlt = ridx - kb;
                if (dlt == 0) v.x = 1.f;
                else if (dlt == 1) v.y = 1.f;
                else if (dlt == 2) v.z = 1.f;
                else if (dlt == 3) v.w = 1.f;
                *(float4*)(erow + kb) = v;          // 1 KiB per wave store
            }
        }
    }
}

// Finalize: vq_loss and perplexity scalars.
__global__ __launch_bounds__(1024) void vq_finalize(
    const int* __restrict__ counts, const float* __restrict__ lossSum,
    float* __restrict__ out)
{
    __shared__ float red[16];
    const int t = threadIdx.x;                     // 1024 threads, one per k
    const float p = (float)counts[t] * (1.0f / 32768.0f);
    float v = p * logf(p + 1e-10f);                // p==0 -> 0 (matches ref)
    #pragma unroll
    for (int off = 32; off; off >>= 1) v += __shfl_down(v, off);
    if ((t & 63) == 0) red[t >> 6] = v;
    __syncthreads();
    if (t == 0) {
        float s = 0.f;
        #pragma unroll
        for (int i = 0; i < 16; ++i) s += red[i];
        out[OUT_OFF_PPL] = expf(-s);
        out[OUT_OFF_VQ] = 1.25f * lossSum[0] * (1.0f / 2097152.0f);
    }
}

extern "C" void kernel_launch(void* const* d_in, const int* in_sizes, int n_in,
                              void* d_out, int out_size, void* d_ws, size_t ws_size,
                              hipStream_t stream) {
    const float* X = (const float*)d_in[0];   // [32, 64, 32, 32] fp32
    const float* E = (const float*)d_in[1];   // [1024, 64] fp32
    float* out = (float*)d_out;
    int* counts = (int*)d_ws;                               // 4 KiB
    float* lossSum = (float*)((char*)d_ws + 4096);          // 4 B

    // zero counts + loss accumulator (ws is poisoned 0xAA each call)
    hipMemsetAsync(d_ws, 0, 8192, stream);

    vq_main<<<512, 512, 0, stream>>>(X, E, out, counts, lossSum);
    vq_finalize<<<1, 1024, 0, stream>>>(counts, lossSum, out);
}

// Round 2
// 211.821 us; speedup vs baseline: 1.2753x; 1.2753x over previous
//
#include <hip/hip_runtime.h>

// Problem constants: B=32, D=64, H=W=32 -> N=32768 rows; K=1024 codes
#define OUT_OFF_Q 0          // quantized (straight-through fwd) [B,D,H,W]
#define OUT_OFF_VQ 2097152   // scalar vq_loss
#define OUT_OFF_PPL 2097153  // scalar perplexity
#define OUT_OFF_ENC 2097154  // encoded one-hot [N, K]

typedef __attribute__((ext_vector_type(8))) short short8;   // 8 bf16 (4 VGPRs)
typedef __attribute__((ext_vector_type(4))) float f32x4;    // MFMA C/D

__device__ __forceinline__ unsigned short f2bf(float f) {   // RNE f32->bf16
    unsigned u = __builtin_bit_cast(unsigned, f);
    u += 0x7fffu + ((u >> 16) & 1u);
    return (unsigned short)(u >> 16);
}
__device__ __forceinline__ float bf2f(unsigned short h) {
    unsigned u = ((unsigned)h) << 16;
    return __builtin_bit_cast(float, u);
}

// ---------------------------------------------------------------------------
// prep: split E into bf16 hi/lo (ws), compute ee[k]=||e_k||^2, zero counters.
// grid 16 x 256 : thread handles 16 d of one k-row (4 threads per row).
__global__ __launch_bounds__(256) void vq_prep(
    const float* __restrict__ E, unsigned short* __restrict__ Ehi,
    unsigned short* __restrict__ Elo, float* __restrict__ ee,
    int* __restrict__ counts, float* __restrict__ lossSum)
{
    const int gid = blockIdx.x * 256 + threadIdx.x;
    const int k = gid >> 2;
    const int part = gid & 3;
    const float* ep = E + k * 64 + part * 16;
    short8 h0, h1, l0, l1;
    float s = 0.f;
    #pragma unroll
    for (int i = 0; i < 16; ++i) {
        float v = ep[i];
        unsigned short hb = f2bf(v);
        unsigned short lb = f2bf(v - bf2f(hb));
        if (i < 8) { h0[i] = (short)hb; l0[i] = (short)lb; }
        else       { h1[i - 8] = (short)hb; l1[i - 8] = (short)lb; }
        s = fmaf(v, v, s);
    }
    *(short8*)(Ehi + k * 64 + part * 16)     = h0;
    *(short8*)(Ehi + k * 64 + part * 16 + 8) = h1;
    *(short8*)(Elo + k * 64 + part * 16)     = l0;
    *(short8*)(Elo + k * 64 + part * 16 + 8) = l1;
    // reduce ||e||^2 over the 4 adjacent lanes
    s += __shfl_xor(s, 1);
    s += __shfl_xor(s, 2);
    if (part == 0) ee[k] = s;
    // zero counters (stream-ordered before vq_main)
    if (gid < 1024) counts[gid] = 0;
    if (gid == 1024) lossSum[0] = 0.f;
}

// ---------------------------------------------------------------------------
// main: 512 blocks x 256 threads. Block owns 64 consecutive n; wave w owns
// k in [w*256,(w+1)*256). Distances via mfma_f32_16x16x32_bf16 with hi/lo
// split (3 products). B-frags (x) held in VGPRs for the whole k-loop.
__global__ __launch_bounds__(256, 2) void vq_main(
    const float* __restrict__ X, const float* __restrict__ E,
    const unsigned short* __restrict__ Ehi, const unsigned short* __restrict__ Elo,
    const float* __restrict__ ee,
    float* __restrict__ out, int* __restrict__ counts,
    float* __restrict__ lossSum)
{
    __shared__ float s_ee[1024];
    __shared__ float s_val[4][64];
    __shared__ int   s_idx[4][64];

    const int t = threadIdx.x;
    const int l = t & 63;
    const int w = __builtin_amdgcn_readfirstlane(t >> 6);
    const int col = l & 15;          // MFMA row/col index within 16-tile
    const int quad = l >> 4;         // MFMA quad
    const int n0 = blockIdx.x * 64;
    const int b = n0 >> 10;          // all 64 n share b (64 | 1024)
    const int hwb = n0 & 1023;

    // stage ee into LDS (float4 per thread)
    ((float4*)s_ee)[t] = ((const float4*)ee)[t];

    // --- build B-fragments (x) for 4 n-tiles x 2 k-steps, hi & lo ---
    // B[k_gemm=d][n]: n = col (+16*nt), d = ks*32 + quad*8 + j
    short8 bh[4][2], bl[4][2];
    const float* xb = X + (size_t)b * 65536 + hwb;
    #pragma unroll
    for (int nt = 0; nt < 4; ++nt) {
        const float* xn = xb + nt * 16 + col;
        #pragma unroll
        for (int ks = 0; ks < 2; ++ks) {
            short8 vh, vl;
            #pragma unroll
            for (int j = 0; j < 8; ++j) {
                float v = xn[(size_t)(ks * 32 + quad * 8 + j) * 1024];
                unsigned short hb = f2bf(v);
                vh[j] = (short)hb;
                vl[j] = (short)f2bf(v - bf2f(hb));
            }
            bh[nt][ks] = vh;
            bl[nt][ks] = vl;
        }
    }

    __syncthreads();   // s_ee ready

    // --- k-loop: 16 tiles of 16 codes each ---
    float best[4] = {3.4e38f, 3.4e38f, 3.4e38f, 3.4e38f};
    int   bidx[4] = {0, 0, 0, 0};
    for (int kt = 0; kt < 16; ++kt) {
        const int kb = w * 256 + kt * 16;
        // A-frags (E rows): A[m=k][d]: m = col, d = ks*32 + quad*8 + j
        const unsigned short* eh = Ehi + (size_t)(kb + col) * 64 + quad * 8;
        const unsigned short* el = Elo + (size_t)(kb + col) * 64 + quad * 8;
        short8 ah0 = *(const short8*)(eh);
        short8 ah1 = *(const short8*)(eh + 32);
        short8 al0 = *(const short8*)(el);
        short8 al1 = *(const short8*)(el + 32);
        f32x4 eev = *((const f32x4*)&s_ee[kb + quad * 4]);
        #pragma unroll
        for (int nt = 0; nt < 4; ++nt) {
            f32x4 c = {0.f, 0.f, 0.f, 0.f};
            c = __builtin_amdgcn_mfma_f32_16x16x32_bf16(ah0, bh[nt][0], c, 0, 0, 0);
            c = __builtin_amdgcn_mfma_f32_16x16x32_bf16(ah1, bh[nt][1], c, 0, 0, 0);
            c = __builtin_amdgcn_mfma_f32_16x16x32_bf16(al0, bh[nt][0], c, 0, 0, 0);
            c = __builtin_amdgcn_mfma_f32_16x16x32_bf16(al1, bh[nt][1], c, 0, 0, 0);
            c = __builtin_amdgcn_mfma_f32_16x16x32_bf16(ah0, bl[nt][0], c, 0, 0, 0);
            c = __builtin_amdgcn_mfma_f32_16x16x32_bf16(ah1, bl[nt][1], c, 0, 0, 0);
            // C/D: col = lane&15 (n), row = quad*4 + r (k within tile)
            #pragma unroll
            for (int r = 0; r < 4; ++r) {
                float val = fmaf(-2.f, c[r], eev[r]);
                int k = kb + quad * 4 + r;
                if (val < best[nt]) { best[nt] = val; bidx[nt] = k; }
            }
        }
    }

    // --- reduce across quads (lanes l, l^16, l^32, l^48 share (nt,col)) ---
    #pragma unroll
    for (int nt = 0; nt < 4; ++nt) {
        float v = best[nt]; int i = bidx[nt];
        float ov = __shfl_xor(v, 16); int oi = __shfl_xor(i, 16);
        if (ov < v || (ov == v && oi < i)) { v = ov; i = oi; }
        ov = __shfl_xor(v, 32); oi = __shfl_xor(i, 32);
        if (ov < v || (ov == v && oi < i)) { v = ov; i = oi; }
        best[nt] = v; bidx[nt] = i;
    }
    // quad q publishes n-tile nt=q: n_local = q*16 + col
    s_val[w][quad * 16 + col] = best[quad];
    s_idx[w][quad * 16 + col] = bidx[quad];
    __syncthreads();

    // --- cross-wave reduce (wave 0), tie-break lowest k ---
    if (w == 0) {
        float fv = s_val[0][l]; int fi0 = s_idx[0][l];
        #pragma unroll
        for (int j = 1; j < 4; ++j) {
            float v = s_val[j][l]; int i = s_idx[j][l];
            if (v < fv || (v == fv && i < fi0)) { fv = v; fi0 = i; }
        }
        s_idx[0][l] = fi0;
    }
    __syncthreads();

    const int fi = s_idx[0][l];    // final code for n = n0 + l

    // --- counts histogram ---
    if (w == 0) atomicAdd(&counts[fi], 1);

    // --- quantized store + loss: wave w handles d in [16w, 16w+16) ---
    {
        float lsum = 0.f;
        const int hw = hwb + l;
        float* op = out + OUT_OFF_Q + (size_t)b * 65536 + hw;
        const float* xp = X + (size_t)b * 65536 + hw;
        const int d0 = w << 4;
        #pragma unroll
        for (int dd = 0; dd < 16; ++dd) {
            const int d = d0 + dd;
            float q = E[((size_t)fi << 6) + d];   // fp32 gather (L2)
            op[(size_t)d * 1024] = q;             // coalesced store
            float xv = xp[(size_t)d * 1024];      // L1 hot
            float diff = q - xv;
            lsum = fmaf(diff, diff, lsum);
        }
        #pragma unroll
        for (int off = 32; off; off >>= 1) lsum += __shfl_down(lsum, off);
        if (l == 0) atomicAdd(lossSum, lsum);
    }

    // --- encoded one-hot: wave w writes rows [16w, 16w+16), coalesced ---
    {
        float* enc = out + OUT_OFF_ENC;
        const int rbase = w << 4;
        for (int rr = 0; rr < 16; ++rr) {
            const int r = rbase + rr;
            const int ridx = s_idx[0][r];
            float* erow = enc + ((size_t)(n0 + r) << 10);
            #pragma unroll
            for (int c4 = 0; c4 < 4; ++c4) {
                const int kb4 = (c4 << 8) + (l << 2);
                float4 v = make_float4(0.f, 0.f, 0.f, 0.f);
                const int dlt = ridx - kb4;
                if (dlt == 0) v.x = 1.f;
                else if (dlt == 1) v.y = 1.f;
                else if (dlt == 2) v.z = 1.f;
                else if (dlt == 3) v.w = 1.f;
                *(float4*)(erow + kb4) = v;
            }
        }
    }
}

// ---------------------------------------------------------------------------
__global__ __launch_bounds__(1024) void vq_finalize(
    const int* __restrict__ counts, const float* __restrict__ lossSum,
    float* __restrict__ out)
{
    __shared__ float red[16];
    const int t = threadIdx.x;
    const float p = (float)counts[t] * (1.0f / 32768.0f);
    float v = p * logf(p + 1e-10f);
    #pragma unroll
    for (int off = 32; off; off >>= 1) v += __shfl_down(v, off);
    if ((t & 63) == 0) red[t >> 6] = v;
    __syncthreads();
    if (t == 0) {
        float s = 0.f;
        #pragma unroll
        for (int i = 0; i < 16; ++i) s += red[i];
        out[OUT_OFF_PPL] = expf(-s);
        out[OUT_OFF_VQ] = 1.25f * lossSum[0] * (1.0f / 2097152.0f);
    }
}

extern "C" void kernel_launch(void* const* d_in, const int* in_sizes, int n_in,
                              void* d_out, int out_size, void* d_ws, size_t ws_size,
                              hipStream_t stream) {
    const float* X = (const float*)d_in[0];   // [32, 64, 32, 32] fp32
    const float* E = (const float*)d_in[1];   // [1024, 64] fp32
    float* out = (float*)d_out;

    // ws layout
    int* counts = (int*)d_ws;                                          // 4 KiB
    float* lossSum = (float*)((char*)d_ws + 4096);                     // 4 B
    float* ee = (float*)((char*)d_ws + 8192);                          // 4 KiB
    unsigned short* Ehi = (unsigned short*)((char*)d_ws + 12288);      // 128 KiB
    unsigned short* Elo = (unsigned short*)((char*)d_ws + 12288 + 131072);

    vq_prep<<<16, 256, 0, stream>>>(E, Ehi, Elo, ee, counts, lossSum);
    vq_main<<<512, 256, 0, stream>>>(X, E, Ehi, Elo, ee, out, counts, lossSum);
    vq_finalize<<<1, 1024, 0, stream>>>(counts, lossSum, out);
}